// Round 2
// baseline (318.087 us; speedup 1.0000x reference)
//
#include <hip/hip_runtime.h>
#include <hip/hip_bf16.h>

// Problem constants
#define NB   16      // batch
#define NC   256     // C_FEAT
#define HF   80
#define WF   80
#define NPIX 6400    // HF*WF
#define ND   64      // C_ILL
#define NK   3       // experts
#define HZ   40
#define WZ   40
#define KD   224     // padded inner dim: 192 (k,d) + 3 bias(p) + 29 zero = 7*32
#define AROWS 512    // 256 gamma rows + 256 beta rows

typedef __bf16 bf16;
typedef __bf16 bf16x8 __attribute__((ext_vector_type(8)));
typedef float  floatx4 __attribute__((ext_vector_type(4)));

// ---------------------------------------------------------------------------
// Kernel 1: pack expert weights into A [512][224] bf16, kd contiguous.
// Row m<256: gamma for c=m.  Row m>=256: beta for c=m-256.
// A[m][kd<192] = W[k= kd>>6][c][d= kd&63]; A[m][192+k] = bias[k][c]; else 0.
// ---------------------------------------------------------------------------
__global__ __launch_bounds__(256) void pack_A_kernel(
    const float* __restrict__ Wg, const float* __restrict__ bg,
    const float* __restrict__ Wb, const float* __restrict__ bb,
    bf16* __restrict__ A)
{
    int idx = blockIdx.x * 256 + threadIdx.x;
    if (idx >= AROWS * KD) return;
    int m  = idx / KD;
    int kd = idx - m * KD;
    int c  = m & (NC - 1);
    const float* W    = (m < NC) ? Wg : Wb;
    const float* bias = (m < NC) ? bg : bb;
    float v = 0.0f;
    if (kd < NK * ND) {
        int k = kd >> 6, d = kd & 63;
        v = W[(k * NC + c) * ND + d];
    } else if (kd < NK * ND + NK) {
        v = bias[(kd - NK * ND) * NC + c];
    }
    A[idx] = (bf16)v;
}

// ---------------------------------------------------------------------------
// Kernel 2: build ZP [b][pix][KD] bf16 (pixel-major, kd contiguous).
// One block per (b, output row h). Phase 1: z_up/p_up for the 80 pixels of
// this row into LDS (bilinear, half-pixel centers, edge clamp == jax resize
// for 2x upsample: out-of-range taps renormalize onto the edge sample).
// Phase 2: coalesced 16B stores of p_up[k]*z_up[d] (+ p rows + zero pad).
// ---------------------------------------------------------------------------
__global__ __launch_bounds__(256) void build_zp_kernel(
    const float* __restrict__ Z, const float* __restrict__ P,
    bf16* __restrict__ ZP)
{
    __shared__ float z_up[WF][ND + 1];  // +1 pad: conflict-free phase-1 writes
    __shared__ float p_up[WF][NK];

    const int bid = blockIdx.x;           // 0 .. NB*HF-1
    const int b   = bid / HF;
    const int h   = bid - b * HF;
    const int t   = threadIdx.x;

    // vertical source coords (uniform across block)
    float srch = 0.5f * (float)h - 0.25f;
    float flh  = floorf(srch);
    float fh   = srch - flh;
    int h0 = (int)flh, h1 = h0 + 1;
    h0 = max(h0, 0); h1 = min(h1, HZ - 1);

    // phase 1a: z_up[w][d], 80*64 = 5120 entries, 20 per thread
    #pragma unroll
    for (int i = 0; i < 20; ++i) {
        int e = t + 256 * i;          // < 5120
        int d = e / WF;
        int w = e - d * WF;
        float srcw = 0.5f * (float)w - 0.25f;
        float flw  = floorf(srcw);
        float fw   = srcw - flw;
        int w0 = (int)flw, w1 = w0 + 1;
        w0 = max(w0, 0); w1 = min(w1, WZ - 1);
        const float* Zr = Z + (size_t)(b * ND + d) * (HZ * WZ);
        float z00 = Zr[h0 * WZ + w0], z01 = Zr[h0 * WZ + w1];
        float z10 = Zr[h1 * WZ + w0], z11 = Zr[h1 * WZ + w1];
        float zi0 = z00 + fw * (z01 - z00);
        float zi1 = z10 + fw * (z11 - z10);
        z_up[w][d] = zi0 + fh * (zi1 - zi0);
    }
    // phase 1b: p_up[w][k], 240 entries
    if (t < WF * NK) {
        int w = t / NK;
        int k = t - w * NK;
        float srcw = 0.5f * (float)w - 0.25f;
        float flw  = floorf(srcw);
        float fw   = srcw - flw;
        int w0 = (int)flw, w1 = w0 + 1;
        w0 = max(w0, 0); w1 = min(w1, WZ - 1);
        const float* Pr = P + (size_t)(b * NK + k) * (HZ * WZ);
        float p00 = Pr[h0 * WZ + w0], p01 = Pr[h0 * WZ + w1];
        float p10 = Pr[h1 * WZ + w0], p11 = Pr[h1 * WZ + w1];
        float pi0 = p00 + fw * (p01 - p00);
        float pi1 = p10 + fw * (p11 - p10);
        p_up[w][k] = pi0 + fh * (pi1 - pi0);
    }
    __syncthreads();

    // phase 2: write 80*224 bf16 = 35840 B contiguous, 16B per store
    bf16* base = ZP + (size_t)(b * NPIX + h * WF) * KD;
    for (int eo = t * 8; eo < WF * KD; eo += 256 * 8) {
        int w   = eo / KD;
        int kd0 = eo - w * KD;       // multiple of 8
        bf16x8 v;
        if (kd0 < NK * ND) {
            int k  = kd0 >> 6;
            int d0 = kd0 & 63;
            float p = p_up[w][k];
            #pragma unroll
            for (int j = 0; j < 8; ++j)
                v[j] = (bf16)(p * z_up[w][d0 + j]);
        } else if (kd0 == NK * ND) {
            #pragma unroll
            for (int j = 0; j < 8; ++j) v[j] = (bf16)0.0f;
            v[0] = (bf16)p_up[w][0];
            v[1] = (bf16)p_up[w][1];
            v[2] = (bf16)p_up[w][2];
        } else {
            #pragma unroll
            for (int j = 0; j < 8; ++j) v[j] = (bf16)0.0f;
        }
        *reinterpret_cast<bf16x8*>(base + eo) = v;
    }
}

// ---------------------------------------------------------------------------
// Kernel 3: GEMM (M=512, N=6400/b, K=224) + fused FiLM epilogue.
// Block: 64 c's (gamma rows c..c+63 AND beta rows 256+c..) x 128 pixels.
// 4 waves: wave=(mq,nh): 32 gamma-c + matching 32 beta-c, 64 pixels.
// No LDS, no syncthreads: A (229 KB) and ZP tiles ride L1/L2.
// mfma_f32_16x16x32_bf16: A-frag A[m=lane&15][k=(lane>>4)*8+j] (16B contig),
// B-frag B[k][n=lane&15] same k-pattern (16B contig in pixel-major ZP),
// D: row=(lane>>4)*4+reg, col=lane&15.
// Output is FLOAT32 (reference output dtype) — round 1 failed because the
// epilogue wrote bf16 into the fp32 buffer.
// ---------------------------------------------------------------------------
__global__ __launch_bounds__(256) void gemm_film_kernel(
    const bf16* __restrict__ A, const bf16* __restrict__ ZP,
    const float* __restrict__ feat, float* __restrict__ out)
{
    const int ntb = blockIdx.x;   // 0..49  pixel tile
    const int ct  = blockIdx.y;   // 0..3   c tile
    const int b   = blockIdx.z;   // 0..15
    const int tid  = threadIdx.x;
    const int lane = tid & 63;
    const int wv   = tid >> 6;
    const int mq   = wv & 1;
    const int nh   = wv >> 1;
    const int l15  = lane & 15;
    const int q    = lane >> 4;

    const int cbase = ct * 64 + mq * 32;
    const int pix0  = ntb * 128 + nh * 64;

    const bf16* ZPb = ZP + (size_t)b * NPIX * KD;

    floatx4 acc[4][4] = {};  // [mt: 0,1 gamma / 2,3 beta][nt]

    const bf16* arow[4];
    arow[0] = A + (size_t)(cbase + l15) * KD;
    arow[1] = A + (size_t)(cbase + 16 + l15) * KD;
    arow[2] = A + (size_t)(NC + cbase + l15) * KD;
    arow[3] = A + (size_t)(NC + cbase + 16 + l15) * KD;
    const bf16* brow[4];
    #pragma unroll
    for (int nt = 0; nt < 4; ++nt)
        brow[nt] = ZPb + (size_t)(pix0 + nt * 16 + l15) * KD;

    for (int kc = 0; kc < 7; ++kc) {
        const int k0 = kc * 32 + q * 8;
        bf16x8 af[4], bfr[4];
        #pragma unroll
        for (int mt = 0; mt < 4; ++mt)
            af[mt] = *reinterpret_cast<const bf16x8*>(arow[mt] + k0);
        #pragma unroll
        for (int nt = 0; nt < 4; ++nt)
            bfr[nt] = *reinterpret_cast<const bf16x8*>(brow[nt] + k0);
        #pragma unroll
        for (int mt = 0; mt < 4; ++mt)
            #pragma unroll
            for (int nt = 0; nt < 4; ++nt)
                acc[mt][nt] = __builtin_amdgcn_mfma_f32_16x16x32_bf16(
                    af[mt], bfr[nt], acc[mt][nt], 0, 0, 0);
    }

    // fused FiLM epilogue: out = feat*(1+gamma) + beta  (fp32 out)
    const float* featb = feat + (size_t)b * NC * NPIX;
    float* outb = out + (size_t)b * NC * NPIX;
    #pragma unroll
    for (int mt = 0; mt < 2; ++mt) {
        #pragma unroll
        for (int r = 0; r < 4; ++r) {
            int c = cbase + mt * 16 + q * 4 + r;
            const float* frow = featb + (size_t)c * NPIX;
            float* orow = outb + (size_t)c * NPIX;
            #pragma unroll
            for (int nt = 0; nt < 4; ++nt) {
                int pix = pix0 + nt * 16 + l15;
                float g  = acc[mt][nt][r];
                float be = acc[mt + 2][nt][r];
                float f  = frow[pix];
                orow[pix] = f * (1.0f + g) + be;
            }
        }
    }
}

// ---------------------------------------------------------------------------
extern "C" void kernel_launch(void* const* d_in, const int* in_sizes, int n_in,
                              void* d_out, int out_size, void* d_ws, size_t ws_size,
                              hipStream_t stream)
{
    (void)in_sizes; (void)n_in; (void)out_size; (void)ws_size;
    const float* feat = (const float*)d_in[0];
    const float* Z    = (const float*)d_in[1];
    const float* P    = (const float*)d_in[2];
    const float* Wg   = (const float*)d_in[3];
    const float* bg   = (const float*)d_in[4];
    const float* Wb   = (const float*)d_in[5];
    const float* bb   = (const float*)d_in[6];

    bf16* ZPw = (bf16*)d_ws;                              // 16*6400*224*2 = 45,875,200 B
    bf16* Apk = ZPw + (size_t)NB * NPIX * KD;             // + 229,376 B
    float* out = (float*)d_out;

    pack_A_kernel<<<(AROWS * KD + 255) / 256, 256, 0, stream>>>(Wg, bg, Wb, bb, Apk);
    build_zp_kernel<<<NB * HF, 256, 0, stream>>>(Z, P, ZPw);

    dim3 grid(NPIX / 128, NC / 64, NB);
    gemm_film_kernel<<<grid, 256, 0, stream>>>(Apk, ZPw, feat, out);
}

// Round 3
// 283.432 us; speedup vs baseline: 1.1223x; 1.1223x over previous
//
#include <hip/hip_runtime.h>
#include <hip/hip_bf16.h>

// Problem constants
#define NB   16      // batch
#define NC   256     // C_FEAT
#define HF   80
#define WF   80
#define NPIX 6400    // HF*WF
#define ND   64      // C_ILL
#define NK   3       // experts
#define HZ   40
#define WZ   40
#define KD   224     // padded inner dim: 192 (k,d) + 3 bias(p) + 29 zero = 7*32
#define NKC  7       // KD/32 k-chunks
#define NPB  400     // NPIX/16 pixel-blocks per batch image
// Swizzled ZP: [b][pb=400][kc=7][lane=64][8] bf16  (1 KB per (pb,kc) chunk)
// Swizzled A : [g=8][kc=7][mt=4][lane=64][8] bf16  (g = ct*2+mq)
#define ZP_B_STRIDE ((size_t)NPB * NKC * 512)   // 1,433,600 elem per batch
#define PB_STRIDE   (NKC * 512)                 // 3584 elem per pixel-block
#define A_G_STRIDE  (NKC * 4 * 512)             // 14336 elem per g

typedef __bf16 bf16;
typedef __bf16 bf16x8 __attribute__((ext_vector_type(8)));
typedef float  floatx4 __attribute__((ext_vector_type(4)));

// ---------------------------------------------------------------------------
// Kernel 1: pack expert weights into swizzled A.
// Chunk i = ((g*7+kc)*4+mt)*64 + lane; lane=(q,l15).
// Row: mt<2 -> gamma c = cbase+mt*16+l15 ; mt>=2 -> beta, same c formula.
// k-range: kd0 = kc*32+q*8; kd<192 = W[k][c][d], kd 192..194 = bias, else 0.
// Wave stores are 1 KB contiguous.
// ---------------------------------------------------------------------------
__global__ __launch_bounds__(256) void pack_A_kernel(
    const float* __restrict__ Wg, const float* __restrict__ bg,
    const float* __restrict__ Wb, const float* __restrict__ bb,
    bf16* __restrict__ A2)
{
    int i = blockIdx.x * 256 + threadIdx.x;   // 0 .. 14335
    int lane = i & 63;
    int j2 = i >> 6;           // 0..223
    int mt = j2 & 3;
    int j3 = j2 >> 2;          // 0..55
    int kc = j3 % 7;
    int g  = j3 / 7;           // 0..7
    int l15 = lane & 15, q = lane >> 4;
    int cbase = (g >> 1) * 64 + (g & 1) * 32;
    int c = cbase + (mt & 1) * 16 + l15;
    const float* W    = (mt >= 2) ? Wb : Wg;
    const float* bias = (mt >= 2) ? bb : bg;
    int kd0 = kc * 32 + q * 8;

    bf16x8 v;
    if (kd0 < NK * ND) {
        int k = kd0 >> 6, d = kd0 & 63;
        const float* src = W + ((size_t)k * NC + c) * ND + d;
        #pragma unroll
        for (int j = 0; j < 8; ++j) v[j] = (bf16)src[j];
    } else if (kd0 == NK * ND) {
        #pragma unroll
        for (int j = 0; j < 8; ++j) v[j] = (bf16)0.0f;
        v[0] = (bf16)bias[0 * NC + c];
        v[1] = (bf16)bias[1 * NC + c];
        v[2] = (bf16)bias[2 * NC + c];
    } else {
        #pragma unroll
        for (int j = 0; j < 8; ++j) v[j] = (bf16)0.0f;
    }
    *reinterpret_cast<bf16x8*>(A2 + (size_t)i * 8) = v;
}

// ---------------------------------------------------------------------------
// Kernel 2: build swizzled ZP. One block per (b, output row h).
// Phase 1: bilinear z_up/p_up for this row into LDS (unroll capped at 4 to
// avoid the 80-loads-in-flight spill that made R2's version ~150 us).
// Phase 2: chunks (pb_local<5, kc<7, lane) -> 1 KB contiguous wave stores.
// ---------------------------------------------------------------------------
__global__ __launch_bounds__(256) void build_zp_kernel(
    const float* __restrict__ Z, const float* __restrict__ P,
    bf16* __restrict__ ZP2)
{
    __shared__ float z_up[WF][ND + 1];
    __shared__ float p_up[WF][NK];

    const int bid = blockIdx.x;           // 0 .. NB*HF-1
    const int b   = bid / HF;
    const int h   = bid - b * HF;
    const int t   = threadIdx.x;

    float srch = 0.5f * (float)h - 0.25f;
    float flh  = floorf(srch);
    float fh   = srch - flh;
    int h0 = (int)flh, h1 = h0 + 1;
    h0 = max(h0, 0); h1 = min(h1, HZ - 1);

    // phase 1a: z_up[w][d], 5120 entries, 20 per thread
    #pragma unroll 4
    for (int i = 0; i < 20; ++i) {
        int e = t + 256 * i;
        int d = e / WF;
        int w = e - d * WF;
        float srcw = 0.5f * (float)w - 0.25f;
        float flw  = floorf(srcw);
        float fw   = srcw - flw;
        int w0 = (int)flw, w1 = w0 + 1;
        w0 = max(w0, 0); w1 = min(w1, WZ - 1);
        const float* Zr = Z + (size_t)(b * ND + d) * (HZ * WZ);
        float z00 = Zr[h0 * WZ + w0], z01 = Zr[h0 * WZ + w1];
        float z10 = Zr[h1 * WZ + w0], z11 = Zr[h1 * WZ + w1];
        float zi0 = z00 + fw * (z01 - z00);
        float zi1 = z10 + fw * (z11 - z10);
        z_up[w][d] = zi0 + fh * (zi1 - zi0);
    }
    // phase 1b: p_up[w][k], 240 entries
    if (t < WF * NK) {
        int w = t / NK;
        int k = t - w * NK;
        float srcw = 0.5f * (float)w - 0.25f;
        float flw  = floorf(srcw);
        float fw   = srcw - flw;
        int w0 = (int)flw, w1 = w0 + 1;
        w0 = max(w0, 0); w1 = min(w1, WZ - 1);
        const float* Pr = P + (size_t)(b * NK + k) * (HZ * WZ);
        float p00 = Pr[h0 * WZ + w0], p01 = Pr[h0 * WZ + w1];
        float p10 = Pr[h1 * WZ + w0], p11 = Pr[h1 * WZ + w1];
        float pi0 = p00 + fw * (p01 - p00);
        float pi1 = p10 + fw * (p11 - p10);
        p_up[w][k] = pi0 + fh * (pi1 - pi0);
    }
    __syncthreads();

    // phase 2: 5 pb * 7 kc * 64 lanes = 2240 chunks of 16 B
    const size_t rowbase = (size_t)(b * (NPB * NKC) + h * 5 * NKC) * 512;
    for (int i = t; i < 5 * NKC * 64; i += 256) {
        int lane = i & 63;
        int j2   = i >> 6;         // 0..34
        int kc   = j2 % NKC;
        int pb_l = j2 / NKC;       // 0..4
        int l15 = lane & 15, q = lane >> 4;
        int w   = pb_l * 16 + l15;
        int kd0 = kc * 32 + q * 8;
        bf16x8 v;
        if (kd0 < NK * ND) {
            int k  = kd0 >> 6;
            int d0 = kd0 & 63;
            float p = p_up[w][k];
            #pragma unroll
            for (int j = 0; j < 8; ++j)
                v[j] = (bf16)(p * z_up[w][d0 + j]);
        } else if (kd0 == NK * ND) {
            #pragma unroll
            for (int j = 0; j < 8; ++j) v[j] = (bf16)0.0f;
            v[0] = (bf16)p_up[w][0];
            v[1] = (bf16)p_up[w][1];
            v[2] = (bf16)p_up[w][2];
        } else {
            #pragma unroll
            for (int j = 0; j < 8; ++j) v[j] = (bf16)0.0f;
        }
        *reinterpret_cast<bf16x8*>(ZP2 + rowbase + ((size_t)(pb_l * NKC + kc) * 64 + lane) * 8) = v;
    }
}

// ---------------------------------------------------------------------------
// Kernel 3: GEMM (M=512, N=6400/b, K=224) + fused FiLM epilogue.
// All fragment loads are now base+lane*16 in the swizzled layouts -> fully
// coalesced 1 KB global_load_dwordx4 per instruction (R2's 448-B-strided
// 16-segment pattern was the latency killer: 1.64 TB/s, MfmaUtil 5.9%).
// ---------------------------------------------------------------------------
__global__ __launch_bounds__(256) void gemm_film_kernel(
    const bf16* __restrict__ A2, const bf16* __restrict__ ZP2,
    const float* __restrict__ feat, float* __restrict__ out)
{
    const int ntb = blockIdx.x;   // 0..49  pixel tile (128 px)
    const int ct  = blockIdx.y;   // 0..3   c tile (64 c)
    const int b   = blockIdx.z;   // 0..15
    const int tid  = threadIdx.x;
    const int lane = tid & 63;
    const int wv   = tid >> 6;
    const int mq   = wv & 1;
    const int nh   = wv >> 1;
    const int l15  = lane & 15;
    const int q    = lane >> 4;

    const int g     = ct * 2 + mq;        // A tile id
    const int cbase = ct * 64 + mq * 32;
    const int pb0   = ntb * 8 + nh * 4;   // first of 4 pixel-blocks
    const int pix0  = pb0 * 16;

    const bf16* aptr = A2 + (size_t)g * A_G_STRIDE + (size_t)lane * 8;
    const bf16* bptr = ZP2 + (size_t)b * ZP_B_STRIDE + (size_t)pb0 * PB_STRIDE
                       + (size_t)lane * 8;

    floatx4 acc[4][4] = {};  // [mt: 0,1 gamma / 2,3 beta][nt]

    for (int kc = 0; kc < NKC; ++kc) {
        bf16x8 af[4], bfr[4];
        #pragma unroll
        for (int mt = 0; mt < 4; ++mt)
            af[mt] = *reinterpret_cast<const bf16x8*>(aptr + mt * 512);
        #pragma unroll
        for (int nt = 0; nt < 4; ++nt)
            bfr[nt] = *reinterpret_cast<const bf16x8*>(bptr + nt * PB_STRIDE);
        aptr += 4 * 512;   // next kc in A tile
        bptr += 512;       // next kc in each pixel-block
        #pragma unroll
        for (int mt = 0; mt < 4; ++mt)
            #pragma unroll
            for (int nt = 0; nt < 4; ++nt)
                acc[mt][nt] = __builtin_amdgcn_mfma_f32_16x16x32_bf16(
                    af[mt], bfr[nt], acc[mt][nt], 0, 0, 0);
    }

    // fused FiLM epilogue: out = feat*(1+gamma) + beta  (fp32)
    const float* featb = feat + (size_t)b * NC * NPIX;
    float* outb = out + (size_t)b * NC * NPIX;
    #pragma unroll
    for (int mt = 0; mt < 2; ++mt) {
        #pragma unroll
        for (int r = 0; r < 4; ++r) {
            int c = cbase + mt * 16 + q * 4 + r;
            const float* frow = featb + (size_t)c * NPIX;
            float* orow = outb + (size_t)c * NPIX;
            #pragma unroll
            for (int nt = 0; nt < 4; ++nt) {
                int pix = pix0 + nt * 16 + l15;
                float gaccum = acc[mt][nt][r];
                float be     = acc[mt + 2][nt][r];
                float f      = frow[pix];
                orow[pix] = f * (1.0f + gaccum) + be;
            }
        }
    }
}

// ---------------------------------------------------------------------------
extern "C" void kernel_launch(void* const* d_in, const int* in_sizes, int n_in,
                              void* d_out, int out_size, void* d_ws, size_t ws_size,
                              hipStream_t stream)
{
    (void)in_sizes; (void)n_in; (void)out_size; (void)ws_size;
    const float* feat = (const float*)d_in[0];
    const float* Z    = (const float*)d_in[1];
    const float* P    = (const float*)d_in[2];
    const float* Wg   = (const float*)d_in[3];
    const float* bg   = (const float*)d_in[4];
    const float* Wb   = (const float*)d_in[5];
    const float* bb   = (const float*)d_in[6];

    bf16* ZPw = (bf16*)d_ws;                              // 45,875,200 B
    bf16* Apk = ZPw + (size_t)NB * ZP_B_STRIDE;           // + 229,376 B
    float* out = (float*)d_out;

    pack_A_kernel<<<56, 256, 0, stream>>>(Wg, bg, Wb, bb, Apk);
    build_zp_kernel<<<NB * HF, 256, 0, stream>>>(Z, P, ZPw);

    dim3 grid(NPIX / 128, NC / 64, NB);
    gemm_film_kernel<<<grid, 256, 0, stream>>>(Apk, ZPw, feat, out);
}